// Round 2
// baseline (231.357 us; speedup 1.0000x reference)
//
#include <hip/hip_runtime.h>

#define L_SEQ   4096
#define D_MODEL 512
#define NSEQ    2048   // BATCH * D_MODEL
#define CH      128    // chunk length
#define NC      32     // chunks

// workspace float offsets
#define OFF_P    0        // P = A^128, [i][j] row-major, 4096
#define OFF_W1T  4096     // W1T[r][i] = (A^{127-r} b)[i], 128x64
#define OFF_WOUT 12288    // Wout[i][r] = (c^T A^{r+1})[i], 64x128
#define OFF_KLOC 20480    // KlocZ[0..127]=0, KlocZ[128+m]=c^T A^m b, 256
#define OFF_GX   20736    // gx[c][s][i]: proj writes G, scan overwrites X_c

#define BC(v, j) __int_as_float(__builtin_amdgcn_readlane(__float_as_int(v), (j)))

// ===========================================================================
// k_prep (1 block): power ladder S=A^{2^t} via 7 squarings; vr/cw tables by
// log-doubling GEMMs against S at each level. (unchanged from prev round)
// ===========================================================================
__global__ __launch_bounds__(256) void k_prep(
    const float* __restrict__ A, const float* __restrict__ B,
    const float* __restrict__ C, float* __restrict__ ws) {
  __shared__ float Srow[64][68];   // S[i][k]
  __shared__ float STs[64][68];    // STs[k][i] = S[i][k]
  __shared__ float vrT[128][68];   // vrT[m][i] = (A^m b)[i]
  __shared__ float cwS[129][68];   // cwS[m][j] = (c^T A^m)[j], m=1..128
  __shared__ float Cs[64], Bsh[64];

  const int tid = threadIdx.x;
  if (tid < 64) { Cs[tid] = C[tid]; Bsh[tid] = B[tid]; }
  for (int e = tid; e < 4096; e += 256) {
    const float a = A[e];
    Srow[e >> 6][e & 63] = a;
    STs[e & 63][e >> 6] = a;
  }
  __syncthreads();

  // seeds: vr[0] = b ; cw[1] = c^T A
  if (tid < 64) {
    vrT[0][tid] = Bsh[tid];
    float acc = 0.f;
#pragma unroll
    for (int k = 0; k < 64; ++k) acc += Cs[k] * STs[tid][k];  // A[k][tid]
    cwS[1][tid] = acc;
  }
  __syncthreads();

  const int iy4 = (tid >> 4) * 4, jx4 = (tid & 15) * 4;

  for (int t = 0; t < 7; ++t) {
    const int nd = 1 << t;

    // ---- extensions using S = A^nd
    if (nd <= 2) {
      const int total = 2 * nd * 64;
      if (tid < total) {
        const int half = (tid >= nd * 64);
        const int o = (tid >> 6) & (nd - 1);
        const int idx = tid & 63;
        float acc = 0.f;
        if (!half) {
#pragma unroll
          for (int k = 0; k < 64; ++k) acc += vrT[o][k] * Srow[idx][k];
          vrT[nd + o][idx] = acc;            // (A^nd vr[o])[idx]
        } else {
#pragma unroll
          for (int k = 0; k < 64; ++k) acc += cwS[1 + o][k] * STs[idx][k];
          cwS[nd + 1 + o][idx] = acc;        // (cw[1+o] A^nd)[idx]
        }
      }
    } else {
      const int tilesPerGemm = nd * 4;       // (nd/4) m-tiles x 16 i-tiles
      for (int tt = tid; tt < 2 * tilesPerGemm; tt += 256) {
        const int half = (tt >= tilesPerGemm);
        const int q = half ? tt - tilesPerGemm : tt;
        const int m0 = (q >> 4) * 4;
        const int i0 = (q & 15) * 4;
        float acc[4][4] = {{0.f}};
        if (!half) {
          // vrT[nd+m][i] = sum_k vrT[m][k] * S[i][k]
#pragma unroll 4
          for (int k = 0; k < 64; k += 4) {
            float a_[4][4];
#pragma unroll
            for (int r = 0; r < 4; ++r)
              *(float4*)&a_[r][0] = *(const float4*)&vrT[m0 + r][k];
#pragma unroll
            for (int kk = 0; kk < 4; ++kk) {
              const float4 b4 = *(const float4*)&STs[k + kk][i0];
#pragma unroll
              for (int r = 0; r < 4; ++r) {
                const float av = a_[r][kk];
                acc[r][0] += av * b4.x; acc[r][1] += av * b4.y;
                acc[r][2] += av * b4.z; acc[r][3] += av * b4.w;
              }
            }
          }
#pragma unroll
          for (int r = 0; r < 4; ++r) {
            float4 v; v.x = acc[r][0]; v.y = acc[r][1]; v.z = acc[r][2]; v.w = acc[r][3];
            *(float4*)&vrT[nd + m0 + r][i0] = v;
          }
        } else {
          // cwS[nd+1+m][j] = sum_k cwS[1+m][k] * S[k][j]
#pragma unroll 4
          for (int k = 0; k < 64; k += 4) {
            float a_[4][4];
#pragma unroll
            for (int r = 0; r < 4; ++r)
              *(float4*)&a_[r][0] = *(const float4*)&cwS[1 + m0 + r][k];
#pragma unroll
            for (int kk = 0; kk < 4; ++kk) {
              const float4 b4 = *(const float4*)&Srow[k + kk][i0];
#pragma unroll
              for (int r = 0; r < 4; ++r) {
                const float av = a_[r][kk];
                acc[r][0] += av * b4.x; acc[r][1] += av * b4.y;
                acc[r][2] += av * b4.z; acc[r][3] += av * b4.w;
              }
            }
          }
#pragma unroll
          for (int r = 0; r < 4; ++r) {
            float4 v; v.x = acc[r][0]; v.y = acc[r][1]; v.z = acc[r][2]; v.w = acc[r][3];
            *(float4*)&cwS[nd + 1 + m0 + r][i0] = v;
          }
        }
      }
    }

    // ---- squaring S -> S^2 in regs
    float sacc[4][4] = {{0.f}};
#pragma unroll 4
    for (int k = 0; k < 64; k += 4) {
      float a_[4][4];
#pragma unroll
      for (int r = 0; r < 4; ++r)
        *(float4*)&a_[r][0] = *(const float4*)&Srow[iy4 + r][k];
#pragma unroll
      for (int kk = 0; kk < 4; ++kk) {
        const float4 b4 = *(const float4*)&Srow[k + kk][jx4];
#pragma unroll
        for (int r = 0; r < 4; ++r) {
          const float av = a_[r][kk];
          sacc[r][0] += av * b4.x; sacc[r][1] += av * b4.y;
          sacc[r][2] += av * b4.z; sacc[r][3] += av * b4.w;
        }
      }
    }
    __syncthreads();   // all reads of S done (ext + squaring)
#pragma unroll
    for (int r = 0; r < 4; ++r) {
      float4 v; v.x = sacc[r][0]; v.y = sacc[r][1]; v.z = sacc[r][2]; v.w = sacc[r][3];
      *(float4*)&Srow[iy4 + r][jx4] = v;
    }
#pragma unroll
    for (int c = 0; c < 4; ++c) {
      float4 v; v.x = sacc[0][c]; v.y = sacc[1][c]; v.z = sacc[2][c]; v.w = sacc[3][c];
      *(float4*)&STs[jx4 + c][iy4] = v;
    }
    __syncthreads();
  }
  // now: Srow = A^128, vrT rows 0..127, cwS rows 1..128

  // P
  float* Pg = ws + OFF_P;
  for (int e = tid; e < 4096; e += 256) Pg[e] = Srow[e >> 6][e & 63];

  // W1T[r][i] = vr[127-r][i]
  float* W1Tg = ws + OFF_W1T;
  for (int e = tid; e < 8192; e += 256) W1Tg[e] = vrT[127 - (e >> 6)][e & 63];

  // Wout[i][r] = cw[r+1][i]
  float* Wg = ws + OFF_WOUT;
  for (int e = tid; e < 8192; e += 256) Wg[e] = cwS[(e & 127) + 1][e >> 7];

  // Kloc: KlocZ[128+m] = sum_i C[i]*vr[m][i]; zeros in front as guard
  float* Kz = ws + OFF_KLOC;
  if (tid < 128) {
    float acc = 0.f;
#pragma unroll
    for (int i = 0; i < 64; ++i) acc += Cs[i] * vrT[tid][i];
    Kz[128 + tid] = acc;
  } else {
    Kz[tid - 128] = 0.f;
  }
}

// ===========================================================================
// k_proj: G[c][s][i] = sum_r W1T[r][i] * u[c*128+r][s]
// 128 threads, 8x8 micro-tiles: 8 i-rows x (4+4) s-cols at stride 64.
// Per kk: 4x ds_read_b128 (a-side broadcast, b-side 2-way = free), 64 FMA.
// ===========================================================================
__global__ __launch_bounds__(128) void k_proj(
    const float* __restrict__ u, const float* __restrict__ wsr,
    float* __restrict__ gx) {
  __shared__ float W1s[128][68];   // W1s[r][i]
  __shared__ float Us[64][132];    // Us[rr][s]

  const int st = blockIdx.x;   // 0..15
  const int c = blockIdx.y;    // 0..31
  const int tid = threadIdx.x;
  const int sgl = st * 128;
  const int bi = sgl >> 9, d0 = sgl & 511;

  const float* W1Tg = wsr + OFF_W1T;
#pragma unroll
  for (int k = 0; k < 16; ++k) {
    const int e = tid + 128 * k;          // float4 index over 128x64
    const int r = e >> 4, i4 = (e & 15) * 4;
    *(float4*)&W1s[r][i4] = *(const float4*)(W1Tg + (size_t)e * 4);
  }

  const float* ub = u + ((size_t)bi * L_SEQ + c * CH) * D_MODEL + d0;
  const int ty = tid >> 4, tx = tid & 15;
  const int iy8 = ty * 8;     // 8 consecutive i per thread
  const int sx4 = tx * 4;     // s cols: sx4..sx4+3 and 64+sx4..64+sx4+3

  float acc[8][8];
#pragma unroll
  for (int r = 0; r < 8; ++r)
#pragma unroll
    for (int cc = 0; cc < 8; ++cc) acc[r][cc] = 0.f;

  for (int h = 0; h < 2; ++h) {
    __syncthreads();
#pragma unroll
    for (int e8 = 0; e8 < 16; ++e8) {
      const int e = tid + 128 * e8;       // float4 over 64x128 u tile
      const int rr = e >> 5, s4 = (e & 31) * 4;
      *(float4*)&Us[rr][s4] =
          *(const float4*)(ub + (size_t)(h * 64 + rr) * D_MODEL + s4);
    }
    __syncthreads();
#pragma unroll 2
    for (int rr = 0; rr < 64; ++rr) {
      const int r = h * 64 + rr;
      const float4 a0 = *(const float4*)&W1s[r][iy8];
      const float4 a1 = *(const float4*)&W1s[r][iy8 + 4];
      const float4 b0 = *(const float4*)&Us[rr][sx4];
      const float4 b1 = *(const float4*)&Us[rr][64 + sx4];
      const float av[8] = {a0.x, a0.y, a0.z, a0.w, a1.x, a1.y, a1.z, a1.w};
      const float bv[8] = {b0.x, b0.y, b0.z, b0.w, b1.x, b1.y, b1.z, b1.w};
#pragma unroll
      for (int ii = 0; ii < 8; ++ii)
#pragma unroll
        for (int jj = 0; jj < 8; ++jj) acc[ii][jj] += av[ii] * bv[jj];
    }
  }

  // write gx[c][s][i] (i contiguous)
  float* gb = gx + ((size_t)c * NSEQ + sgl) * 64;
#pragma unroll
  for (int grp = 0; grp < 2; ++grp)
#pragma unroll
    for (int j = 0; j < 4; ++j) {
      const int s = grp * 64 + sx4 + j;
      const int jj = grp * 4 + j;
      float4 v0, v1;
      v0.x = acc[0][jj]; v0.y = acc[1][jj]; v0.z = acc[2][jj]; v0.w = acc[3][jj];
      v1.x = acc[4][jj]; v1.y = acc[5][jj]; v1.z = acc[6][jj]; v1.w = acc[7][jj];
      float* row = gb + (size_t)s * 64 + iy8;
      *(float4*)row = v0;
      *(float4*)(row + 4) = v1;
    }
}

// ===========================================================================
// k_scan: x_{c+1} = P x_c + g_c. One seq per wave, lane = state.
// 3-deep chunk prefetch pipeline. (unchanged from prev round)
// ===========================================================================
__global__ __launch_bounds__(256) void k_scan(
    const float* __restrict__ wsr, float* __restrict__ gx) {
  const int lane = threadIdx.x & 63, wv = threadIdx.x >> 6;
  const int s = blockIdx.x * 4 + wv;

  float p[64];
  {
    const float* pr = wsr + OFF_P + lane * 64;
#pragma unroll
    for (int j = 0; j < 64; j += 4) {
      const float4 v = *(const float4*)(pr + j);
      p[j] = v.x; p[j + 1] = v.y; p[j + 2] = v.z; p[j + 3] = v.w;
    }
  }

  const size_t CS = (size_t)NSEQ * 64;
  float* gs = gx + (size_t)s * 64 + lane;
  float x = 0.f;
  float g0 = gs[0];
  float g1 = gs[CS];
  float g2 = gs[2 * CS];
  for (int c = 0; c < NC; ++c) {
    const float gn = (c + 3 < NC) ? gs[(size_t)(c + 3) * CS] : 0.f;
    gs[(size_t)c * CS] = x;  // overwrite g[c] with pre-chunk state X_c
    float x0 = g0, x1 = 0.f;
#pragma unroll
    for (int j = 0; j < 64; j += 2) {
      x0 += p[j] * BC(x, j);
      x1 += p[j + 1] * BC(x, j + 1);
    }
    x = x0 + x1;
    g0 = g1; g1 = g2; g2 = gn;
  }
}

// ===========================================================================
// k_localout: y[c*128+r][s] = sum_{r'<=r} Kloc[r-r'] u[c*128+r'][s]
//                           + sum_i Wout[i][r] * X_c[i][s]
// 64 rows x 128 seqs per block, 128 threads, 8x8 micro-tiles (4+4 s-split).
// ===========================================================================
__global__ __launch_bounds__(128) void k_localout(
    const float* __restrict__ u, const float* __restrict__ wsr,
    const float* __restrict__ gx, float* __restrict__ out) {
  __shared__ float As[64][68];    // As[k][row]
  __shared__ float Bs[64][132];   // Bs[k][s]

  const int sg = blockIdx.x;      // 0..15 (128 seqs each)
  const int tr = blockIdx.y;      // 0..63 (64 rows each)
  const int c = tr >> 1, par = tr & 1;
  const int r0 = par * 64;
  const int sgl = sg * 128;
  const int bi = sgl >> 9, d0 = sgl & 511;

  const float* KlocZ = wsr + OFF_KLOC;
  const float* WoutG = wsr + OFF_WOUT;
  const float* ub = u + ((size_t)bi * L_SEQ + c * CH) * D_MODEL + d0;

  const int tid = threadIdx.x;
  const int ty = tid >> 4, tx = tid & 15;
  const int ry8 = ty * 8;     // 8 consecutive output rows per thread
  const int sx4 = tx * 4;     // s cols: sx4.. and 64+sx4..

  float acc[8][8];
#pragma unroll
  for (int r = 0; r < 8; ++r)
#pragma unroll
    for (int cc = 0; cc < 8; ++cc) acc[r][cc] = 0.f;

  // phase A: within-chunk Toeplitz part
  for (int kt = 0; kt <= par; ++kt) {
    const int k0 = kt * 64;
#pragma unroll
    for (int e8 = 0; e8 < 16; ++e8) {
      const int e = tid + 128 * e8;          // float4 over 64x128 u tile
      const int kk = e >> 5, s4 = (e & 31) * 4;
      *(float4*)&Bs[kk][s4] = *(const float4*)(ub + (size_t)(k0 + kk) * D_MODEL + s4);
    }
    const int base = 128 + r0 - k0;
#pragma unroll
    for (int e4 = 0; e4 < 32; ++e4) {
      const int e = tid + 128 * e4;
      const int kk = e >> 6, i = e & 63;
      As[kk][i] = KlocZ[base + i - kk];      // zero-guarded Toeplitz
    }
    __syncthreads();
#pragma unroll 2
    for (int kk = 0; kk < 64; ++kk) {
      const float4 a0 = *(const float4*)&As[kk][ry8];
      const float4 a1 = *(const float4*)&As[kk][ry8 + 4];
      const float4 b0 = *(const float4*)&Bs[kk][sx4];
      const float4 b1 = *(const float4*)&Bs[kk][64 + sx4];
      const float av[8] = {a0.x, a0.y, a0.z, a0.w, a1.x, a1.y, a1.z, a1.w};
      const float bv[8] = {b0.x, b0.y, b0.z, b0.w, b1.x, b1.y, b1.z, b1.w};
#pragma unroll
      for (int ii = 0; ii < 8; ++ii)
#pragma unroll
        for (int jj = 0; jj < 8; ++jj) acc[ii][jj] += av[ii] * bv[jj];
    }
    __syncthreads();
  }

  // phase B: Wout * X_c  (X from gx[c][s][i] via float4 + LDS transpose)
  {
    const float* xc = gx + ((size_t)c * NSEQ + sgl) * 64;
#pragma unroll
    for (int e8 = 0; e8 < 16; ++e8) {
      const int e = tid + 128 * e8;          // 2048 float4 = 8192 elems
      const int sl = e >> 4, i4 = (e & 15) * 4;
      const float4 v = *(const float4*)(xc + (size_t)sl * 64 + i4);
      Bs[i4 + 0][sl] = v.x;
      Bs[i4 + 1][sl] = v.y;
      Bs[i4 + 2][sl] = v.z;
      Bs[i4 + 3][sl] = v.w;
    }
#pragma unroll
    for (int e4 = 0; e4 < 8; ++e4) {
      const int e = tid + 128 * e4;          // float4 over 64x64 Wout slice
      const int i_ = e >> 4, r4 = (e & 15) * 4;
      *(float4*)&As[i_][r4] = *(const float4*)(WoutG + i_ * 128 + r0 + r4);
    }
    __syncthreads();
#pragma unroll 2
    for (int kk = 0; kk < 64; ++kk) {
      const float4 a0 = *(const float4*)&As[kk][ry8];
      const float4 a1 = *(const float4*)&As[kk][ry8 + 4];
      const float4 b0 = *(const float4*)&Bs[kk][sx4];
      const float4 b1 = *(const float4*)&Bs[kk][64 + sx4];
      const float av[8] = {a0.x, a0.y, a0.z, a0.w, a1.x, a1.y, a1.z, a1.w};
      const float bv[8] = {b0.x, b0.y, b0.z, b0.w, b1.x, b1.y, b1.z, b1.w};
#pragma unroll
      for (int ii = 0; ii < 8; ++ii)
#pragma unroll
        for (int jj = 0; jj < 8; ++jj) acc[ii][jj] += av[ii] * bv[jj];
    }
  }

  // epilogue: rows ry8..ry8+7, cols sx4.. and 64+sx4..
  float* ob = out + ((size_t)bi * L_SEQ + c * CH + r0) * D_MODEL + d0;
#pragma unroll
  for (int r = 0; r < 8; ++r) {
    float4 v0, v1;
    v0.x = acc[r][0]; v0.y = acc[r][1]; v0.z = acc[r][2]; v0.w = acc[r][3];
    v1.x = acc[r][4]; v1.y = acc[r][5]; v1.z = acc[r][6]; v1.w = acc[r][7];
    float* row = ob + (size_t)(ry8 + r) * D_MODEL;
    *(float4*)(row + sx4) = v0;
    *(float4*)(row + 64 + sx4) = v1;
  }
}

extern "C" void kernel_launch(void* const* d_in, const int* in_sizes, int n_in,
                              void* d_out, int out_size, void* d_ws,
                              size_t ws_size, hipStream_t stream) {
  const float* u = (const float*)d_in[0];   // (4, 4096, 512)
  const float* A = (const float*)d_in[1];   // (64, 64)
  const float* B = (const float*)d_in[2];   // (64, 1)
  const float* C = (const float*)d_in[3];   // (1, 64)
  float* out = (float*)d_out;
  float* ws = (float*)d_ws;                 // needs ~16.9 MB
  float* gx = ws + OFF_GX;

  k_prep<<<1, 256, 0, stream>>>(A, B, C, ws);
  k_proj<<<dim3(16, 32), 128, 0, stream>>>(u, ws, gx);
  k_scan<<<512, 256, 0, stream>>>(ws, gx);
  k_localout<<<dim3(16, 64), 128, 0, stream>>>(u, ws, gx, out);
}

// Round 4
// 219.582 us; speedup vs baseline: 1.0536x; 1.0536x over previous
//
#include <hip/hip_runtime.h>

#define L_SEQ   4096
#define D_MODEL 512
#define NSEQ    2048   // BATCH * D_MODEL
#define CH      128    // chunk length
#define NC      32     // chunks

// workspace float offsets
#define OFF_P    0        // P = A^128, [i][j] row-major, 4096
#define OFF_W1T  4096     // W1T[r][i] = (A^{127-r} b)[i], 128x64
#define OFF_WOUT 12288    // Wout[i][r] = (c^T A^{r+1})[i], 64x128
#define OFF_KLOC 20480    // KlocZ[0..127]=0, KlocZ[128+m]=c^T A^m b, 256
#define OFF_GX   20736    // gx[c][s][i]: proj writes G, scan overwrites X_c

#define BC(v, j) __int_as_float(__builtin_amdgcn_readlane(__float_as_int(v), (j)))

// ===========================================================================
// k_prep (1 block): power ladder S=A^{2^t} via 7 squarings; vr/cw tables by
// log-doubling GEMMs against S at each level. (unchanged)
// ===========================================================================
__global__ __launch_bounds__(256) void k_prep(
    const float* __restrict__ A, const float* __restrict__ B,
    const float* __restrict__ C, float* __restrict__ ws) {
  __shared__ float Srow[64][68];   // S[i][k]
  __shared__ float STs[64][68];    // STs[k][i] = S[i][k]
  __shared__ float vrT[128][68];   // vrT[m][i] = (A^m b)[i]
  __shared__ float cwS[129][68];   // cwS[m][j] = (c^T A^m)[j], m=1..128
  __shared__ float Cs[64], Bsh[64];

  const int tid = threadIdx.x;
  if (tid < 64) { Cs[tid] = C[tid]; Bsh[tid] = B[tid]; }
  for (int e = tid; e < 4096; e += 256) {
    const float a = A[e];
    Srow[e >> 6][e & 63] = a;
    STs[e & 63][e >> 6] = a;
  }
  __syncthreads();

  // seeds: vr[0] = b ; cw[1] = c^T A
  if (tid < 64) {
    vrT[0][tid] = Bsh[tid];
    float acc = 0.f;
#pragma unroll
    for (int k = 0; k < 64; ++k) acc += Cs[k] * STs[tid][k];  // A[k][tid]
    cwS[1][tid] = acc;
  }
  __syncthreads();

  const int iy4 = (tid >> 4) * 4, jx4 = (tid & 15) * 4;

  for (int t = 0; t < 7; ++t) {
    const int nd = 1 << t;

    // ---- extensions using S = A^nd
    if (nd <= 2) {
      const int total = 2 * nd * 64;
      if (tid < total) {
        const int half = (tid >= nd * 64);
        const int o = (tid >> 6) & (nd - 1);
        const int idx = tid & 63;
        float acc = 0.f;
        if (!half) {
#pragma unroll
          for (int k = 0; k < 64; ++k) acc += vrT[o][k] * Srow[idx][k];
          vrT[nd + o][idx] = acc;            // (A^nd vr[o])[idx]
        } else {
#pragma unroll
          for (int k = 0; k < 64; ++k) acc += cwS[1 + o][k] * STs[idx][k];
          cwS[nd + 1 + o][idx] = acc;        // (cw[1+o] A^nd)[idx]
        }
      }
    } else {
      const int tilesPerGemm = nd * 4;       // (nd/4) m-tiles x 16 i-tiles
      for (int tt = tid; tt < 2 * tilesPerGemm; tt += 256) {
        const int half = (tt >= tilesPerGemm);
        const int q = half ? tt - tilesPerGemm : tt;
        const int m0 = (q >> 4) * 4;
        const int i0 = (q & 15) * 4;
        float acc[4][4] = {{0.f}};
        if (!half) {
          // vrT[nd+m][i] = sum_k vrT[m][k] * S[i][k]
#pragma unroll 4
          for (int k = 0; k < 64; k += 4) {
            float a_[4][4];
#pragma unroll
            for (int r = 0; r < 4; ++r)
              *(float4*)&a_[r][0] = *(const float4*)&vrT[m0 + r][k];
#pragma unroll
            for (int kk = 0; kk < 4; ++kk) {
              const float4 b4 = *(const float4*)&STs[k + kk][i0];
#pragma unroll
              for (int r = 0; r < 4; ++r) {
                const float av = a_[r][kk];
                acc[r][0] += av * b4.x; acc[r][1] += av * b4.y;
                acc[r][2] += av * b4.z; acc[r][3] += av * b4.w;
              }
            }
          }
#pragma unroll
          for (int r = 0; r < 4; ++r) {
            float4 v; v.x = acc[r][0]; v.y = acc[r][1]; v.z = acc[r][2]; v.w = acc[r][3];
            *(float4*)&vrT[nd + m0 + r][i0] = v;
          }
        } else {
          // cwS[nd+1+m][j] = sum_k cwS[1+m][k] * S[k][j]
#pragma unroll 4
          for (int k = 0; k < 64; k += 4) {
            float a_[4][4];
#pragma unroll
            for (int r = 0; r < 4; ++r)
              *(float4*)&a_[r][0] = *(const float4*)&cwS[1 + m0 + r][k];
#pragma unroll
            for (int kk = 0; kk < 4; ++kk) {
              const float4 b4 = *(const float4*)&Srow[k + kk][i0];
#pragma unroll
              for (int r = 0; r < 4; ++r) {
                const float av = a_[r][kk];
                acc[r][0] += av * b4.x; acc[r][1] += av * b4.y;
                acc[r][2] += av * b4.z; acc[r][3] += av * b4.w;
              }
            }
          }
#pragma unroll
          for (int r = 0; r < 4; ++r) {
            float4 v; v.x = acc[r][0]; v.y = acc[r][1]; v.z = acc[r][2]; v.w = acc[r][3];
            *(float4*)&cwS[nd + 1 + m0 + r][i0] = v;
          }
        }
      }
    }

    // ---- squaring S -> S^2 in regs
    float sacc[4][4] = {{0.f}};
#pragma unroll 4
    for (int k = 0; k < 64; k += 4) {
      float a_[4][4];
#pragma unroll
      for (int r = 0; r < 4; ++r)
        *(float4*)&a_[r][0] = *(const float4*)&Srow[iy4 + r][k];
#pragma unroll
      for (int kk = 0; kk < 4; ++kk) {
        const float4 b4 = *(const float4*)&Srow[k + kk][jx4];
#pragma unroll
        for (int r = 0; r < 4; ++r) {
          const float av = a_[r][kk];
          sacc[r][0] += av * b4.x; sacc[r][1] += av * b4.y;
          sacc[r][2] += av * b4.z; sacc[r][3] += av * b4.w;
        }
      }
    }
    __syncthreads();   // all reads of S done (ext + squaring)
#pragma unroll
    for (int r = 0; r < 4; ++r) {
      float4 v; v.x = sacc[r][0]; v.y = sacc[r][1]; v.z = sacc[r][2]; v.w = sacc[r][3];
      *(float4*)&Srow[iy4 + r][jx4] = v;
    }
#pragma unroll
    for (int c = 0; c < 4; ++c) {
      float4 v; v.x = sacc[0][c]; v.y = sacc[1][c]; v.z = sacc[2][c]; v.w = sacc[3][c];
      *(float4*)&STs[jx4 + c][iy4] = v;
    }
    __syncthreads();
  }
  // now: Srow = A^128, vrT rows 0..127, cwS rows 1..128

  // P
  float* Pg = ws + OFF_P;
  for (int e = tid; e < 4096; e += 256) Pg[e] = Srow[e >> 6][e & 63];

  // W1T[r][i] = vr[127-r][i]
  float* W1Tg = ws + OFF_W1T;
  for (int e = tid; e < 8192; e += 256) W1Tg[e] = vrT[127 - (e >> 6)][e & 63];

  // Wout[i][r] = cw[r+1][i]
  float* Wg = ws + OFF_WOUT;
  for (int e = tid; e < 8192; e += 256) Wg[e] = cwS[(e & 127) + 1][e >> 7];

  // Kloc: KlocZ[128+m] = sum_i C[i]*vr[m][i]; zeros in front as guard
  float* Kz = ws + OFF_KLOC;
  if (tid < 128) {
    float acc = 0.f;
#pragma unroll
    for (int i = 0; i < 64; ++i) acc += Cs[i] * vrT[tid][i];
    Kz[128 + tid] = acc;
  } else {
    Kz[tid - 128] = 0.f;
  }
}

// ===========================================================================
// k_proj: G[c][s][i] = sum_r W1T[r][i] * u[c*128+r][s]
// 256 threads, 4x8 micro-tiles (round-1 structure; per-wave LDS reads span
// <=64-float windows -> conflict-free).
// ===========================================================================
__global__ __launch_bounds__(256) void k_proj(
    const float* __restrict__ u, const float* __restrict__ wsr,
    float* __restrict__ gx) {
  __shared__ float W1s[128][66];
  __shared__ float Us[64][132];

  const int st = blockIdx.x;   // 0..15
  const int c = blockIdx.y;    // 0..31
  const int tid = threadIdx.x;
  const int sgl = st * 128;
  const int bi = sgl >> 9, d0 = sgl & 511;

  const float* W1Tg = wsr + OFF_W1T;
#pragma unroll
  for (int k = 0; k < 32; ++k) {
    const int e = tid + 256 * k;
    W1s[e >> 6][e & 63] = W1Tg[e];
  }

  const float* ub = u + ((size_t)bi * L_SEQ + c * CH) * D_MODEL + d0;
  const int sy4 = (tid >> 3) * 4;   // s-row group (0..31)*4
  const int ix8 = (tid & 7) * 8;    // i-col group (0..7)*8

  float acc[4][8];
#pragma unroll
  for (int r = 0; r < 4; ++r)
#pragma unroll
    for (int cc = 0; cc < 8; ++cc) acc[r][cc] = 0.f;

  for (int h = 0; h < 2; ++h) {
    __syncthreads();
#pragma unroll
    for (int e8 = 0; e8 < 8; ++e8) {
      const int e = tid + 256 * e8;
      const int rr = e >> 5, s4 = (e & 31) * 4;
      *(float4*)&Us[rr][s4] =
          *(const float4*)(ub + (size_t)(h * 64 + rr) * D_MODEL + s4);
    }
    __syncthreads();
#pragma unroll 4
    for (int rr = 0; rr < 64; ++rr) {
      const int r = h * 64 + rr;
      const float4 a = *(const float4*)&Us[rr][sy4];
      const float4 b0 = *(const float4*)&W1s[r][ix8];
      const float4 b1 = *(const float4*)&W1s[r][ix8 + 4];
      acc[0][0] += a.x * b0.x; acc[0][1] += a.x * b0.y; acc[0][2] += a.x * b0.z; acc[0][3] += a.x * b0.w;
      acc[0][4] += a.x * b1.x; acc[0][5] += a.x * b1.y; acc[0][6] += a.x * b1.z; acc[0][7] += a.x * b1.w;
      acc[1][0] += a.y * b0.x; acc[1][1] += a.y * b0.y; acc[1][2] += a.y * b0.z; acc[1][3] += a.y * b0.w;
      acc[1][4] += a.y * b1.x; acc[1][5] += a.y * b1.y; acc[1][6] += a.y * b1.z; acc[1][7] += a.y * b1.w;
      acc[2][0] += a.z * b0.x; acc[2][1] += a.z * b0.y; acc[2][2] += a.z * b0.z; acc[2][3] += a.z * b0.w;
      acc[2][4] += a.z * b1.x; acc[2][5] += a.z * b1.y; acc[2][6] += a.z * b1.z; acc[2][7] += a.z * b1.w;
      acc[3][0] += a.w * b0.x; acc[3][1] += a.w * b0.y; acc[3][2] += a.w * b0.z; acc[3][3] += a.w * b0.w;
      acc[3][4] += a.w * b1.x; acc[3][5] += a.w * b1.y; acc[3][6] += a.w * b1.z; acc[3][7] += a.w * b1.w;
    }
  }

  float* gb = gx + ((size_t)c * NSEQ + sgl) * 64;
#pragma unroll
  for (int as = 0; as < 4; ++as) {
    float4 v0, v1;
    v0.x = acc[as][0]; v0.y = acc[as][1]; v0.z = acc[as][2]; v0.w = acc[as][3];
    v1.x = acc[as][4]; v1.y = acc[as][5]; v1.z = acc[as][6]; v1.w = acc[as][7];
    float* row = gb + (size_t)(sy4 + as) * 64 + ix8;
    *(float4*)row = v0;
    *(float4*)(row + 4) = v1;
  }
}

// ===========================================================================
// k_scan: x_{c+1} = P x_c + g_c. One seq per wave, lane = state.
// 3-deep chunk prefetch pipeline. (unchanged)
// ===========================================================================
__global__ __launch_bounds__(256) void k_scan(
    const float* __restrict__ wsr, float* __restrict__ gx) {
  const int lane = threadIdx.x & 63, wv = threadIdx.x >> 6;
  const int s = blockIdx.x * 4 + wv;

  float p[64];
  {
    const float* pr = wsr + OFF_P + lane * 64;
#pragma unroll
    for (int j = 0; j < 64; j += 4) {
      const float4 v = *(const float4*)(pr + j);
      p[j] = v.x; p[j + 1] = v.y; p[j + 2] = v.z; p[j + 3] = v.w;
    }
  }

  const size_t CS = (size_t)NSEQ * 64;
  float* gs = gx + (size_t)s * 64 + lane;
  float x = 0.f;
  float g0 = gs[0];
  float g1 = gs[CS];
  float g2 = gs[2 * CS];
  for (int c = 0; c < NC; ++c) {
    const float gn = (c + 3 < NC) ? gs[(size_t)(c + 3) * CS] : 0.f;
    gs[(size_t)c * CS] = x;  // overwrite g[c] with pre-chunk state X_c
    float x0 = g0, x1 = 0.f;
#pragma unroll
    for (int j = 0; j < 64; j += 2) {
      x0 += p[j] * BC(x, j);
      x1 += p[j + 1] * BC(x, j + 1);
    }
    x = x0 + x1;
    g0 = g1; g1 = g2; g2 = gn;
  }
}

// ===========================================================================
// k_localout: y[c*128+r][s] = sum_{r'<=r} Kloc[r-r'] u[c*128+r'][s]
//                           + sum_i Wout[i][r] * X_c[i][s]
// MERGED: 128 rows x 128 seqs per block (full chunk), 256 threads, 8x8
// micro-tiles with 4+4 s-split at stride 64 (conflict-free) and per-wave
// 32-row bands. Zero-guarded Toeplitz makes K=128 valid for all rows.
// LDS 67.6 KB -> 2 blocks/CU = 8 waves/CU. Explicit kk+1 register prefetch.
// ===========================================================================
__global__ __launch_bounds__(256) void k_localout(
    const float* __restrict__ u, const float* __restrict__ wsr,
    const float* __restrict__ gx, float* __restrict__ out) {
  __shared__ float As[64][132];   // As[k][row], rows 0..127
  __shared__ float Bs[64][132];   // Bs[k][s],   s 0..127

  const int sg = blockIdx.x;      // 0..15 (128 seqs each)
  const int c = blockIdx.y;       // 0..31 (chunk)
  const int sgl = sg * 128;
  const int bi = sgl >> 9, d0 = sgl & 511;

  const float* KlocZ = wsr + OFF_KLOC;
  const float* WoutG = wsr + OFF_WOUT;
  const float* ub = u + ((size_t)bi * L_SEQ + c * CH) * D_MODEL + d0;

  const int tid = threadIdx.x;
  const int lane = tid & 63, w = tid >> 6;
  const int ry8 = (w * 4 + (lane >> 4)) * 8;  // 8 rows, wave-band w*32..+31
  const int sx4 = (lane & 15) * 4;            // s cols: sx4.. and 64+sx4..

  float acc[8][8];
#pragma unroll
  for (int r = 0; r < 8; ++r)
#pragma unroll
    for (int cc = 0; cc < 8; ++cc) acc[r][cc] = 0.f;

  // phase A: within-chunk Toeplitz, K = 128 in two 64-k stages
  for (int kt = 0; kt < 2; ++kt) {
    const int k0 = kt * 64;
#pragma unroll
    for (int e8 = 0; e8 < 8; ++e8) {
      const int e = tid + 256 * e8;          // 2048 float4 over 64x128 u tile
      const int kk = e >> 5, s4 = (e & 31) * 4;
      *(float4*)&Bs[kk][s4] = *(const float4*)(ub + (size_t)(k0 + kk) * D_MODEL + s4);
    }
    const int base = 128 - k0;
#pragma unroll
    for (int e4 = 0; e4 < 32; ++e4) {
      const int e = tid + 256 * e4;          // 8192 scalars over 64x128
      const int kk = e >> 7, r = e & 127;
      As[kk][r] = KlocZ[base + r - kk];      // zero-guarded Toeplitz
    }
    __syncthreads();
    {
      float4 a0 = *(const float4*)&As[0][ry8];
      float4 a1 = *(const float4*)&As[0][ry8 + 4];
      float4 b0 = *(const float4*)&Bs[0][sx4];
      float4 b1 = *(const float4*)&Bs[0][64 + sx4];
#pragma unroll 8
      for (int kk = 0; kk < 64; ++kk) {
        float4 na0 = a0, na1 = a1, nb0 = b0, nb1 = b1;
        if (kk < 63) {
          na0 = *(const float4*)&As[kk + 1][ry8];
          na1 = *(const float4*)&As[kk + 1][ry8 + 4];
          nb0 = *(const float4*)&Bs[kk + 1][sx4];
          nb1 = *(const float4*)&Bs[kk + 1][64 + sx4];
        }
        const float av[8] = {a0.x, a0.y, a0.z, a0.w, a1.x, a1.y, a1.z, a1.w};
        const float bv[8] = {b0.x, b0.y, b0.z, b0.w, b1.x, b1.y, b1.z, b1.w};
#pragma unroll
        for (int ii = 0; ii < 8; ++ii)
#pragma unroll
          for (int jj = 0; jj < 8; ++jj) acc[ii][jj] += av[ii] * bv[jj];
        a0 = na0; a1 = na1; b0 = nb0; b1 = nb1;
      }
    }
    __syncthreads();
  }

  // phase B: Wout * X_c  (X from gx[c][s][i] via float4 + LDS transpose)
  {
    const float* xc = gx + ((size_t)c * NSEQ + sgl) * 64;
#pragma unroll
    for (int e8 = 0; e8 < 8; ++e8) {
      const int e = tid + 256 * e8;          // 2048 float4 = 8192 elems
      const int sl = e >> 4, i4 = (e & 15) * 4;
      const float4 v = *(const float4*)(xc + (size_t)sl * 64 + i4);
      Bs[i4 + 0][sl] = v.x;
      Bs[i4 + 1][sl] = v.y;
      Bs[i4 + 2][sl] = v.z;
      Bs[i4 + 3][sl] = v.w;
    }
#pragma unroll
    for (int e4 = 0; e4 < 8; ++e4) {
      const int e = tid + 256 * e4;          // 2048 float4 over 64x128 Wout
      const int i_ = e >> 5, r4 = (e & 31) * 4;
      *(float4*)&As[i_][r4] = *(const float4*)(WoutG + i_ * 128 + r4);
    }
    __syncthreads();
    {
      float4 a0 = *(const float4*)&As[0][ry8];
      float4 a1 = *(const float4*)&As[0][ry8 + 4];
      float4 b0 = *(const float4*)&Bs[0][sx4];
      float4 b1 = *(const float4*)&Bs[0][64 + sx4];
#pragma unroll 8
      for (int kk = 0; kk < 64; ++kk) {
        float4 na0 = a0, na1 = a1, nb0 = b0, nb1 = b1;
        if (kk < 63) {
          na0 = *(const float4*)&As[kk + 1][ry8];
          na1 = *(const float4*)&As[kk + 1][ry8 + 4];
          nb0 = *(const float4*)&Bs[kk + 1][sx4];
          nb1 = *(const float4*)&Bs[kk + 1][64 + sx4];
        }
        const float av[8] = {a0.x, a0.y, a0.z, a0.w, a1.x, a1.y, a1.z, a1.w};
        const float bv[8] = {b0.x, b0.y, b0.z, b0.w, b1.x, b1.y, b1.z, b1.w};
#pragma unroll
        for (int ii = 0; ii < 8; ++ii)
#pragma unroll
          for (int jj = 0; jj < 8; ++jj) acc[ii][jj] += av[ii] * bv[jj];
        a0 = na0; a1 = na1; b0 = nb0; b1 = nb1;
      }
    }
  }

  // epilogue: rows ry8..ry8+7, cols sx4.. and 64+sx4..
  float* ob = out + ((size_t)bi * L_SEQ + c * CH) * D_MODEL + d0;
#pragma unroll
  for (int r = 0; r < 8; ++r) {
    float4 v0, v1;
    v0.x = acc[r][0]; v0.y = acc[r][1]; v0.z = acc[r][2]; v0.w = acc[r][3];
    v1.x = acc[r][4]; v1.y = acc[r][5]; v1.z = acc[r][6]; v1.w = acc[r][7];
    float* row = ob + (size_t)(ry8 + r) * D_MODEL;
    *(float4*)(row + sx4) = v0;
    *(float4*)(row + 64 + sx4) = v1;
  }
}

extern "C" void kernel_launch(void* const* d_in, const int* in_sizes, int n_in,
                              void* d_out, int out_size, void* d_ws,
                              size_t ws_size, hipStream_t stream) {
  const float* u = (const float*)d_in[0];   // (4, 4096, 512)
  const float* A = (const float*)d_in[1];   // (64, 64)
  const float* B = (const float*)d_in[2];   // (64, 1)
  const float* C = (const float*)d_in[3];   // (1, 64)
  float* out = (float*)d_out;
  float* ws = (float*)d_ws;                 // needs ~16.9 MB
  float* gx = ws + OFF_GX;

  k_prep<<<1, 256, 0, stream>>>(A, B, C, ws);
  k_proj<<<dim3(16, 32), 256, 0, stream>>>(u, ws, gx);
  k_scan<<<512, 256, 0, stream>>>(ws, gx);
  k_localout<<<dim3(16, 32), 256, 0, stream>>>(u, ws, gx, out);
}

// Round 5
// 201.733 us; speedup vs baseline: 1.1469x; 1.0885x over previous
//
#include <hip/hip_runtime.h>

#define L_SEQ   4096
#define D_MODEL 512
#define NSEQ    2048   // BATCH * D_MODEL
#define CH      128    // chunk length
#define NC      32     // chunks

// workspace float offsets
#define OFF_P    0        // P = A^128, [i][j] row-major, 4096
#define OFF_W1T  4096     // W1T[r][i] = (A^{127-r} b)[i], 128x64
#define OFF_WOUT 12288    // Wout[i][r] = (c^T A^{r+1})[i], 64x128
#define OFF_KLOC 20480    // KlocZ[0..127]=0, KlocZ[128+m]=c^T A^m b, 256
#define OFF_GX   20736    // gx[c][s][i]: proj writes G, scan overwrites X_c

#define BC(v, j) __int_as_float(__builtin_amdgcn_readlane(__float_as_int(v), (j)))

// ===========================================================================
// k_prep (1 block): power ladder S=A^{2^t} via 7 squarings; vr/cw tables by
// log-doubling GEMMs against S at each level. (unchanged)
// ===========================================================================
__global__ __launch_bounds__(256) void k_prep(
    const float* __restrict__ A, const float* __restrict__ B,
    const float* __restrict__ C, float* __restrict__ ws) {
  __shared__ float Srow[64][68];   // S[i][k]
  __shared__ float STs[64][68];    // STs[k][i] = S[i][k]
  __shared__ float vrT[128][68];   // vrT[m][i] = (A^m b)[i]
  __shared__ float cwS[129][68];   // cwS[m][j] = (c^T A^m)[j], m=1..128
  __shared__ float Cs[64], Bsh[64];

  const int tid = threadIdx.x;
  if (tid < 64) { Cs[tid] = C[tid]; Bsh[tid] = B[tid]; }
  for (int e = tid; e < 4096; e += 256) {
    const float a = A[e];
    Srow[e >> 6][e & 63] = a;
    STs[e & 63][e >> 6] = a;
  }
  __syncthreads();

  // seeds: vr[0] = b ; cw[1] = c^T A
  if (tid < 64) {
    vrT[0][tid] = Bsh[tid];
    float acc = 0.f;
#pragma unroll
    for (int k = 0; k < 64; ++k) acc += Cs[k] * STs[tid][k];  // A[k][tid]
    cwS[1][tid] = acc;
  }
  __syncthreads();

  const int iy4 = (tid >> 4) * 4, jx4 = (tid & 15) * 4;

  for (int t = 0; t < 7; ++t) {
    const int nd = 1 << t;

    // ---- extensions using S = A^nd
    if (nd <= 2) {
      const int total = 2 * nd * 64;
      if (tid < total) {
        const int half = (tid >= nd * 64);
        const int o = (tid >> 6) & (nd - 1);
        const int idx = tid & 63;
        float acc = 0.f;
        if (!half) {
#pragma unroll
          for (int k = 0; k < 64; ++k) acc += vrT[o][k] * Srow[idx][k];
          vrT[nd + o][idx] = acc;            // (A^nd vr[o])[idx]
        } else {
#pragma unroll
          for (int k = 0; k < 64; ++k) acc += cwS[1 + o][k] * STs[idx][k];
          cwS[nd + 1 + o][idx] = acc;        // (cw[1+o] A^nd)[idx]
        }
      }
    } else {
      const int tilesPerGemm = nd * 4;       // (nd/4) m-tiles x 16 i-tiles
      for (int tt = tid; tt < 2 * tilesPerGemm; tt += 256) {
        const int half = (tt >= tilesPerGemm);
        const int q = half ? tt - tilesPerGemm : tt;
        const int m0 = (q >> 4) * 4;
        const int i0 = (q & 15) * 4;
        float acc[4][4] = {{0.f}};
        if (!half) {
          // vrT[nd+m][i] = sum_k vrT[m][k] * S[i][k]
#pragma unroll 4
          for (int k = 0; k < 64; k += 4) {
            float a_[4][4];
#pragma unroll
            for (int r = 0; r < 4; ++r)
              *(float4*)&a_[r][0] = *(const float4*)&vrT[m0 + r][k];
#pragma unroll
            for (int kk = 0; kk < 4; ++kk) {
              const float4 b4 = *(const float4*)&STs[k + kk][i0];
#pragma unroll
              for (int r = 0; r < 4; ++r) {
                const float av = a_[r][kk];
                acc[r][0] += av * b4.x; acc[r][1] += av * b4.y;
                acc[r][2] += av * b4.z; acc[r][3] += av * b4.w;
              }
            }
          }
#pragma unroll
          for (int r = 0; r < 4; ++r) {
            float4 v; v.x = acc[r][0]; v.y = acc[r][1]; v.z = acc[r][2]; v.w = acc[r][3];
            *(float4*)&vrT[nd + m0 + r][i0] = v;
          }
        } else {
          // cwS[nd+1+m][j] = sum_k cwS[1+m][k] * S[k][j]
#pragma unroll 4
          for (int k = 0; k < 64; k += 4) {
            float a_[4][4];
#pragma unroll
            for (int r = 0; r < 4; ++r)
              *(float4*)&a_[r][0] = *(const float4*)&cwS[1 + m0 + r][k];
#pragma unroll
            for (int kk = 0; kk < 4; ++kk) {
              const float4 b4 = *(const float4*)&Srow[k + kk][i0];
#pragma unroll
              for (int r = 0; r < 4; ++r) {
                const float av = a_[r][kk];
                acc[r][0] += av * b4.x; acc[r][1] += av * b4.y;
                acc[r][2] += av * b4.z; acc[r][3] += av * b4.w;
              }
            }
          }
#pragma unroll
          for (int r = 0; r < 4; ++r) {
            float4 v; v.x = acc[r][0]; v.y = acc[r][1]; v.z = acc[r][2]; v.w = acc[r][3];
            *(float4*)&cwS[nd + 1 + m0 + r][i0] = v;
          }
        }
      }
    }

    // ---- squaring S -> S^2 in regs
    float sacc[4][4] = {{0.f}};
#pragma unroll 4
    for (int k = 0; k < 64; k += 4) {
      float a_[4][4];
#pragma unroll
      for (int r = 0; r < 4; ++r)
        *(float4*)&a_[r][0] = *(const float4*)&Srow[iy4 + r][k];
#pragma unroll
      for (int kk = 0; kk < 4; ++kk) {
        const float4 b4 = *(const float4*)&Srow[k + kk][jx4];
#pragma unroll
        for (int r = 0; r < 4; ++r) {
          const float av = a_[r][kk];
          sacc[r][0] += av * b4.x; sacc[r][1] += av * b4.y;
          sacc[r][2] += av * b4.z; sacc[r][3] += av * b4.w;
        }
      }
    }
    __syncthreads();   // all reads of S done (ext + squaring)
#pragma unroll
    for (int r = 0; r < 4; ++r) {
      float4 v; v.x = sacc[r][0]; v.y = sacc[r][1]; v.z = sacc[r][2]; v.w = sacc[r][3];
      *(float4*)&Srow[iy4 + r][jx4] = v;
    }
#pragma unroll
    for (int c = 0; c < 4; ++c) {
      float4 v; v.x = sacc[0][c]; v.y = sacc[1][c]; v.z = sacc[2][c]; v.w = sacc[3][c];
      *(float4*)&STs[jx4 + c][iy4] = v;
    }
    __syncthreads();
  }
  // now: Srow = A^128, vrT rows 0..127, cwS rows 1..128

  // P
  float* Pg = ws + OFF_P;
  for (int e = tid; e < 4096; e += 256) Pg[e] = Srow[e >> 6][e & 63];

  // W1T[r][i] = vr[127-r][i]
  float* W1Tg = ws + OFF_W1T;
  for (int e = tid; e < 8192; e += 256) W1Tg[e] = vrT[127 - (e >> 6)][e & 63];

  // Wout[i][r] = cw[r+1][i]
  float* Wg = ws + OFF_WOUT;
  for (int e = tid; e < 8192; e += 256) Wg[e] = cwS[(e & 127) + 1][e >> 7];

  // Kloc: KlocZ[128+m] = sum_i C[i]*vr[m][i]; zeros in front as guard
  float* Kz = ws + OFF_KLOC;
  if (tid < 128) {
    float acc = 0.f;
#pragma unroll
    for (int i = 0; i < 64; ++i) acc += Cs[i] * vrT[tid][i];
    Kz[128 + tid] = acc;
  } else {
    Kz[tid - 128] = 0.f;
  }
}

// ===========================================================================
// k_proj: G[c][s][i] = sum_r W1T[r][i] * u[c*128+r][s]
// 256 threads, 4x8 micro-tiles. (unchanged)
// ===========================================================================
__global__ __launch_bounds__(256) void k_proj(
    const float* __restrict__ u, const float* __restrict__ wsr,
    float* __restrict__ gx) {
  __shared__ float W1s[128][66];
  __shared__ float Us[64][132];

  const int st = blockIdx.x;   // 0..15
  const int c = blockIdx.y;    // 0..31
  const int tid = threadIdx.x;
  const int sgl = st * 128;
  const int bi = sgl >> 9, d0 = sgl & 511;

  const float* W1Tg = wsr + OFF_W1T;
#pragma unroll
  for (int k = 0; k < 32; ++k) {
    const int e = tid + 256 * k;
    W1s[e >> 6][e & 63] = W1Tg[e];
  }

  const float* ub = u + ((size_t)bi * L_SEQ + c * CH) * D_MODEL + d0;
  const int sy4 = (tid >> 3) * 4;   // s-row group (0..31)*4
  const int ix8 = (tid & 7) * 8;    // i-col group (0..7)*8

  float acc[4][8];
#pragma unroll
  for (int r = 0; r < 4; ++r)
#pragma unroll
    for (int cc = 0; cc < 8; ++cc) acc[r][cc] = 0.f;

  for (int h = 0; h < 2; ++h) {
    __syncthreads();
#pragma unroll
    for (int e8 = 0; e8 < 8; ++e8) {
      const int e = tid + 256 * e8;
      const int rr = e >> 5, s4 = (e & 31) * 4;
      *(float4*)&Us[rr][s4] =
          *(const float4*)(ub + (size_t)(h * 64 + rr) * D_MODEL + s4);
    }
    __syncthreads();
#pragma unroll 4
    for (int rr = 0; rr < 64; ++rr) {
      const int r = h * 64 + rr;
      const float4 a = *(const float4*)&Us[rr][sy4];
      const float4 b0 = *(const float4*)&W1s[r][ix8];
      const float4 b1 = *(const float4*)&W1s[r][ix8 + 4];
      acc[0][0] += a.x * b0.x; acc[0][1] += a.x * b0.y; acc[0][2] += a.x * b0.z; acc[0][3] += a.x * b0.w;
      acc[0][4] += a.x * b1.x; acc[0][5] += a.x * b1.y; acc[0][6] += a.x * b1.z; acc[0][7] += a.x * b1.w;
      acc[1][0] += a.y * b0.x; acc[1][1] += a.y * b0.y; acc[1][2] += a.y * b0.z; acc[1][3] += a.y * b0.w;
      acc[1][4] += a.y * b1.x; acc[1][5] += a.y * b1.y; acc[1][6] += a.y * b1.z; acc[1][7] += a.y * b1.w;
      acc[2][0] += a.z * b0.x; acc[2][1] += a.z * b0.y; acc[2][2] += a.z * b0.z; acc[2][3] += a.z * b0.w;
      acc[2][4] += a.z * b1.x; acc[2][5] += a.z * b1.y; acc[2][6] += a.z * b1.z; acc[2][7] += a.z * b1.w;
      acc[3][0] += a.w * b0.x; acc[3][1] += a.w * b0.y; acc[3][2] += a.w * b0.z; acc[3][3] += a.w * b0.w;
      acc[3][4] += a.w * b1.x; acc[3][5] += a.w * b1.y; acc[3][6] += a.w * b1.z; acc[3][7] += a.w * b1.w;
    }
  }

  float* gb = gx + ((size_t)c * NSEQ + sgl) * 64;
#pragma unroll
  for (int as = 0; as < 4; ++as) {
    float4 v0, v1;
    v0.x = acc[as][0]; v0.y = acc[as][1]; v0.z = acc[as][2]; v0.w = acc[as][3];
    v1.x = acc[as][4]; v1.y = acc[as][5]; v1.z = acc[as][6]; v1.w = acc[as][7];
    float* row = gb + (size_t)(sy4 + as) * 64 + ix8;
    *(float4*)row = v0;
    *(float4*)(row + 4) = v1;
  }
}

// ===========================================================================
// k_scan: x_{c+1} = P x_c + g_c. One seq per wave, lane = state.
// 3-deep chunk prefetch pipeline. (unchanged)
// ===========================================================================
__global__ __launch_bounds__(256) void k_scan(
    const float* __restrict__ wsr, float* __restrict__ gx) {
  const int lane = threadIdx.x & 63, wv = threadIdx.x >> 6;
  const int s = blockIdx.x * 4 + wv;

  float p[64];
  {
    const float* pr = wsr + OFF_P + lane * 64;
#pragma unroll
    for (int j = 0; j < 64; j += 4) {
      const float4 v = *(const float4*)(pr + j);
      p[j] = v.x; p[j + 1] = v.y; p[j + 2] = v.z; p[j + 3] = v.w;
    }
  }

  const size_t CS = (size_t)NSEQ * 64;
  float* gs = gx + (size_t)s * 64 + lane;
  float x = 0.f;
  float g0 = gs[0];
  float g1 = gs[CS];
  float g2 = gs[2 * CS];
  for (int c = 0; c < NC; ++c) {
    const float gn = (c + 3 < NC) ? gs[(size_t)(c + 3) * CS] : 0.f;
    gs[(size_t)c * CS] = x;  // overwrite g[c] with pre-chunk state X_c
    float x0 = g0, x1 = 0.f;
#pragma unroll
    for (int j = 0; j < 64; j += 2) {
      x0 += p[j] * BC(x, j);
      x1 += p[j + 1] * BC(x, j + 1);
    }
    x = x0 + x1;
    g0 = g1; g1 = g2; g2 = gn;
  }
}

// ===========================================================================
// k_localout: y[c*128+r][s] = sum_{r'<=r} Kloc[r-r'] u[c*128+r'][s]
//                           + sum_i Wout[i][r] * X_c[i][s]
// 128 rows x 128 seqs per block (full chunk), 256 threads, 8x8 micro-tiles
// (4+4 s-split at stride 64, conflict-free). PLAIN inner loop (compiler
// pipelines the unrolled body; hand prefetch with runtime guards regressed).
// Stage kt=1 skipped by waves owning rows <64 (wave-uniform; contributions
// provably zero via the KlocZ guard) -> no wasted FLOPs vs split blocks.
// LDS 67.6 KB -> 2 blocks/CU = 8 waves/CU.
// ===========================================================================
__global__ __launch_bounds__(256) void k_localout(
    const float* __restrict__ u, const float* __restrict__ wsr,
    const float* __restrict__ gx, float* __restrict__ out) {
  __shared__ float As[64][132];   // As[k][row], rows 0..127
  __shared__ float Bs[64][132];   // Bs[k][s],   s 0..127

  const int sg = blockIdx.x;      // 0..15 (128 seqs each)
  const int c = blockIdx.y;       // 0..31 (chunk)
  const int sgl = sg * 128;
  const int bi = sgl >> 9, d0 = sgl & 511;

  const float* KlocZ = wsr + OFF_KLOC;
  const float* WoutG = wsr + OFF_WOUT;
  const float* ub = u + ((size_t)bi * L_SEQ + c * CH) * D_MODEL + d0;

  const int tid = threadIdx.x;
  const int lane = tid & 63, w = tid >> 6;
  const int ry8 = (w * 4 + (lane >> 4)) * 8;  // 8 rows, wave-band w*32..+31
  const int sx4 = (lane & 15) * 4;            // s cols: sx4.. and 64+sx4..

  float acc[8][8];
#pragma unroll
  for (int r = 0; r < 8; ++r)
#pragma unroll
    for (int cc = 0; cc < 8; ++cc) acc[r][cc] = 0.f;

  // phase A: within-chunk Toeplitz, K = 128 in two 64-k stages
  for (int kt = 0; kt < 2; ++kt) {
    const int k0 = kt * 64;
#pragma unroll
    for (int e8 = 0; e8 < 8; ++e8) {
      const int e = tid + 256 * e8;          // 2048 float4 over 64x128 u tile
      const int kk = e >> 5, s4 = (e & 31) * 4;
      *(float4*)&Bs[kk][s4] = *(const float4*)(ub + (size_t)(k0 + kk) * D_MODEL + s4);
    }
    const int base = 128 - k0;
#pragma unroll
    for (int e4 = 0; e4 < 32; ++e4) {
      const int e = tid + 256 * e4;          // 8192 scalars over 64x128
      const int kk = e >> 7, r = e & 127;
      As[kk][r] = KlocZ[base + r - kk];      // zero-guarded Toeplitz
    }
    __syncthreads();
    // kt=1: rows <64 have zero contribution (KlocZ idx <=127 = guard zone);
    // skip is wave-uniform (ry8 constant per 32-row wave band).
    if (kt == 0 || ry8 >= 64) {
#pragma unroll 8
      for (int kk = 0; kk < 64; ++kk) {
        const float4 a0 = *(const float4*)&As[kk][ry8];
        const float4 a1 = *(const float4*)&As[kk][ry8 + 4];
        const float4 b0 = *(const float4*)&Bs[kk][sx4];
        const float4 b1 = *(const float4*)&Bs[kk][64 + sx4];
        const float av[8] = {a0.x, a0.y, a0.z, a0.w, a1.x, a1.y, a1.z, a1.w};
        const float bv[8] = {b0.x, b0.y, b0.z, b0.w, b1.x, b1.y, b1.z, b1.w};
#pragma unroll
        for (int ii = 0; ii < 8; ++ii)
#pragma unroll
          for (int jj = 0; jj < 8; ++jj) acc[ii][jj] += av[ii] * bv[jj];
      }
    }
    __syncthreads();
  }

  // phase B: Wout * X_c  (X from gx[c][s][i] via float4 + LDS transpose)
  {
    const float* xc = gx + ((size_t)c * NSEQ + sgl) * 64;
#pragma unroll
    for (int e8 = 0; e8 < 8; ++e8) {
      const int e = tid + 256 * e8;          // 2048 float4 = 8192 elems
      const int sl = e >> 4, i4 = (e & 15) * 4;
      const float4 v = *(const float4*)(xc + (size_t)sl * 64 + i4);
      Bs[i4 + 0][sl] = v.x;
      Bs[i4 + 1][sl] = v.y;
      Bs[i4 + 2][sl] = v.z;
      Bs[i4 + 3][sl] = v.w;
    }
#pragma unroll
    for (int e4 = 0; e4 < 8; ++e4) {
      const int e = tid + 256 * e4;          // 2048 float4 over 64x128 Wout
      const int i_ = e >> 5, r4 = (e & 31) * 4;
      *(float4*)&As[i_][r4] = *(const float4*)(WoutG + i_ * 128 + r4);
    }
    __syncthreads();
#pragma unroll 8
    for (int kk = 0; kk < 64; ++kk) {
      const float4 a0 = *(const float4*)&As[kk][ry8];
      const float4 a1 = *(const float4*)&As[kk][ry8 + 4];
      const float4 b0 = *(const float4*)&Bs[kk][sx4];
      const float4 b1 = *(const float4*)&Bs[kk][64 + sx4];
      const float av[8] = {a0.x, a0.y, a0.z, a0.w, a1.x, a1.y, a1.z, a1.w};
      const float bv[8] = {b0.x, b0.y, b0.z, b0.w, b1.x, b1.y, b1.z, b1.w};
#pragma unroll
      for (int ii = 0; ii < 8; ++ii)
#pragma unroll
        for (int jj = 0; jj < 8; ++jj) acc[ii][jj] += av[ii] * bv[jj];
    }
  }

  // epilogue: rows ry8..ry8+7, cols sx4.. and 64+sx4..
  float* ob = out + ((size_t)bi * L_SEQ + c * CH) * D_MODEL + d0;
#pragma unroll
  for (int r = 0; r < 8; ++r) {
    float4 v0, v1;
    v0.x = acc[r][0]; v0.y = acc[r][1]; v0.z = acc[r][2]; v0.w = acc[r][3];
    v1.x = acc[r][4]; v1.y = acc[r][5]; v1.z = acc[r][6]; v1.w = acc[r][7];
    float* row = ob + (size_t)(ry8 + r) * D_MODEL;
    *(float4*)(row + sx4) = v0;
    *(float4*)(row + 64 + sx4) = v1;
  }
}

extern "C" void kernel_launch(void* const* d_in, const int* in_sizes, int n_in,
                              void* d_out, int out_size, void* d_ws,
                              size_t ws_size, hipStream_t stream) {
  const float* u = (const float*)d_in[0];   // (4, 4096, 512)
  const float* A = (const float*)d_in[1];   // (64, 64)
  const float* B = (const float*)d_in[2];   // (64, 1)
  const float* C = (const float*)d_in[3];   // (1, 64)
  float* out = (float*)d_out;
  float* ws = (float*)d_ws;                 // needs ~16.9 MB
  float* gx = ws + OFF_GX;

  k_prep<<<1, 256, 0, stream>>>(A, B, C, ws);
  k_proj<<<dim3(16, 32), 256, 0, stream>>>(u, ws, gx);
  k_scan<<<512, 256, 0, stream>>>(ws, gx);
  k_localout<<<dim3(16, 32), 256, 0, stream>>>(u, ws, gx, out);
}

// Round 6
// 193.287 us; speedup vs baseline: 1.1970x; 1.0437x over previous
//
#include <hip/hip_runtime.h>

#define L_SEQ   4096
#define D_MODEL 512
#define NSEQ    2048   // BATCH * D_MODEL
#define CH      128    // chunk length
#define NC      32     // chunks

// workspace float offsets
#define OFF_P    0        // P = A^128, [i][j] row-major, 4096
#define OFF_W1T  4096     // W1T[r][i] = (A^{127-r} b)[i], 128x64
#define OFF_WOUT 12288    // Wout[i][r] = (c^T A^{r+1})[i], 64x128
#define OFF_KLOC 20480    // KlocZ[0..127]=0, KlocZ[128+m]=c^T A^m b, 256
#define OFF_KZS  20736    // KzS[p][m] = KlocZ[m-p], 4x256 (aligned shift copies)
#define OFF_GX   21760    // gx[c][s][i]: proj writes G, scan overwrites X_c

#define BC(v, j) __int_as_float(__builtin_amdgcn_readlane(__float_as_int(v), (j)))

// ===========================================================================
// k_prep (1 block): power ladder S=A^{2^t} via 7 squarings; vr/cw tables by
// log-doubling GEMMs. Adds KzS (4 shift-copies of the local kernel vector)
// so k_localout can read Toeplitz rows as aligned float4 without a 32KB As.
// ===========================================================================
__global__ __launch_bounds__(256) void k_prep(
    const float* __restrict__ A, const float* __restrict__ B,
    const float* __restrict__ C, float* __restrict__ ws) {
  __shared__ float Srow[64][68];   // S[i][k]
  __shared__ float STs[64][68];    // STs[k][i] = S[i][k]
  __shared__ float vrT[128][68];   // vrT[m][i] = (A^m b)[i]
  __shared__ float cwS[129][68];   // cwS[m][j] = (c^T A^m)[j], m=1..128
  __shared__ float Cs[64], Bsh[64];
  __shared__ float KzSh[256];

  const int tid = threadIdx.x;
  if (tid < 64) { Cs[tid] = C[tid]; Bsh[tid] = B[tid]; }
  for (int e = tid; e < 4096; e += 256) {
    const float a = A[e];
    Srow[e >> 6][e & 63] = a;
    STs[e & 63][e >> 6] = a;
  }
  __syncthreads();

  // seeds: vr[0] = b ; cw[1] = c^T A
  if (tid < 64) {
    vrT[0][tid] = Bsh[tid];
    float acc = 0.f;
#pragma unroll
    for (int k = 0; k < 64; ++k) acc += Cs[k] * STs[tid][k];  // A[k][tid]
    cwS[1][tid] = acc;
  }
  __syncthreads();

  const int iy4 = (tid >> 4) * 4, jx4 = (tid & 15) * 4;

  for (int t = 0; t < 7; ++t) {
    const int nd = 1 << t;

    // ---- extensions using S = A^nd
    if (nd <= 2) {
      const int total = 2 * nd * 64;
      if (tid < total) {
        const int half = (tid >= nd * 64);
        const int o = (tid >> 6) & (nd - 1);
        const int idx = tid & 63;
        float acc = 0.f;
        if (!half) {
#pragma unroll
          for (int k = 0; k < 64; ++k) acc += vrT[o][k] * Srow[idx][k];
          vrT[nd + o][idx] = acc;            // (A^nd vr[o])[idx]
        } else {
#pragma unroll
          for (int k = 0; k < 64; ++k) acc += cwS[1 + o][k] * STs[idx][k];
          cwS[nd + 1 + o][idx] = acc;        // (cw[1+o] A^nd)[idx]
        }
      }
    } else {
      const int tilesPerGemm = nd * 4;       // (nd/4) m-tiles x 16 i-tiles
      for (int tt = tid; tt < 2 * tilesPerGemm; tt += 256) {
        const int half = (tt >= tilesPerGemm);
        const int q = half ? tt - tilesPerGemm : tt;
        const int m0 = (q >> 4) * 4;
        const int i0 = (q & 15) * 4;
        float acc[4][4] = {{0.f}};
        if (!half) {
          // vrT[nd+m][i] = sum_k vrT[m][k] * S[i][k]
#pragma unroll 4
          for (int k = 0; k < 64; k += 4) {
            float a_[4][4];
#pragma unroll
            for (int r = 0; r < 4; ++r)
              *(float4*)&a_[r][0] = *(const float4*)&vrT[m0 + r][k];
#pragma unroll
            for (int kk = 0; kk < 4; ++kk) {
              const float4 b4 = *(const float4*)&STs[k + kk][i0];
#pragma unroll
              for (int r = 0; r < 4; ++r) {
                const float av = a_[r][kk];
                acc[r][0] += av * b4.x; acc[r][1] += av * b4.y;
                acc[r][2] += av * b4.z; acc[r][3] += av * b4.w;
              }
            }
          }
#pragma unroll
          for (int r = 0; r < 4; ++r) {
            float4 v; v.x = acc[r][0]; v.y = acc[r][1]; v.z = acc[r][2]; v.w = acc[r][3];
            *(float4*)&vrT[nd + m0 + r][i0] = v;
          }
        } else {
          // cwS[nd+1+m][j] = sum_k cwS[1+m][k] * S[k][j]
#pragma unroll 4
          for (int k = 0; k < 64; k += 4) {
            float a_[4][4];
#pragma unroll
            for (int r = 0; r < 4; ++r)
              *(float4*)&a_[r][0] = *(const float4*)&cwS[1 + m0 + r][k];
#pragma unroll
            for (int kk = 0; kk < 4; ++kk) {
              const float4 b4 = *(const float4*)&Srow[k + kk][i0];
#pragma unroll
              for (int r = 0; r < 4; ++r) {
                const float av = a_[r][kk];
                acc[r][0] += av * b4.x; acc[r][1] += av * b4.y;
                acc[r][2] += av * b4.z; acc[r][3] += av * b4.w;
              }
            }
          }
#pragma unroll
          for (int r = 0; r < 4; ++r) {
            float4 v; v.x = acc[r][0]; v.y = acc[r][1]; v.z = acc[r][2]; v.w = acc[r][3];
            *(float4*)&cwS[nd + 1 + m0 + r][i0] = v;
          }
        }
      }
    }

    // ---- squaring S -> S^2 in regs
    float sacc[4][4] = {{0.f}};
#pragma unroll 4
    for (int k = 0; k < 64; k += 4) {
      float a_[4][4];
#pragma unroll
      for (int r = 0; r < 4; ++r)
        *(float4*)&a_[r][0] = *(const float4*)&Srow[iy4 + r][k];
#pragma unroll
      for (int kk = 0; kk < 4; ++kk) {
        const float4 b4 = *(const float4*)&Srow[k + kk][jx4];
#pragma unroll
        for (int r = 0; r < 4; ++r) {
          const float av = a_[r][kk];
          sacc[r][0] += av * b4.x; sacc[r][1] += av * b4.y;
          sacc[r][2] += av * b4.z; sacc[r][3] += av * b4.w;
        }
      }
    }
    __syncthreads();   // all reads of S done (ext + squaring)
#pragma unroll
    for (int r = 0; r < 4; ++r) {
      float4 v; v.x = sacc[r][0]; v.y = sacc[r][1]; v.z = sacc[r][2]; v.w = sacc[r][3];
      *(float4*)&Srow[iy4 + r][jx4] = v;
    }
#pragma unroll
    for (int c = 0; c < 4; ++c) {
      float4 v; v.x = sacc[0][c]; v.y = sacc[1][c]; v.z = sacc[2][c]; v.w = sacc[3][c];
      *(float4*)&STs[jx4 + c][iy4] = v;
    }
    __syncthreads();
  }
  // now: Srow = A^128, vrT rows 0..127, cwS rows 1..128

  // P
  float* Pg = ws + OFF_P;
  for (int e = tid; e < 4096; e += 256) Pg[e] = Srow[e >> 6][e & 63];

  // W1T[r][i] = vr[127-r][i]
  float* W1Tg = ws + OFF_W1T;
  for (int e = tid; e < 8192; e += 256) W1Tg[e] = vrT[127 - (e >> 6)][e & 63];

  // Wout[i][r] = cw[r+1][i]
  float* Wg = ws + OFF_WOUT;
  for (int e = tid; e < 8192; e += 256) Wg[e] = cwS[(e & 127) + 1][e >> 7];

  // Kloc: KzSh[128+m] = sum_i C[i]*vr[m][i]; zeros in front as guard
  float* Kz = ws + OFF_KLOC;
  if (tid < 128) {
    float acc = 0.f;
#pragma unroll
    for (int i = 0; i < 64; ++i) acc += Cs[i] * vrT[tid][i];
    KzSh[128 + tid] = acc;
    Kz[128 + tid] = acc;
  } else {
    KzSh[tid - 128] = 0.f;
    Kz[tid - 128] = 0.f;
  }
  __syncthreads();

  // KzS[p][m] = KzSh[m - p] (p = 0..3 alignment shifts)
  float* KzSg = ws + OFF_KZS;
  for (int e = tid; e < 1024; e += 256) {
    const int p = e >> 8, m = e & 255;
    KzSg[e] = (m >= p) ? KzSh[m - p] : 0.f;
  }
}

// ===========================================================================
// k_proj: G[c][s][i] = sum_r W1T[r][i] * u[c*128+r][s]
// 64s x 64i tile, 256 threads, 4x4 micro. LDS = W1s 32K + Us 16K = 48KB
// -> 3 blocks/CU; grid 1024 -> 3 waves/SIMD (was 2).
// ===========================================================================
__global__ __launch_bounds__(256) void k_proj(
    const float* __restrict__ u, const float* __restrict__ wsr,
    float* __restrict__ gx) {
  __shared__ float W1s[128][64];
  __shared__ float Us[64][64];

  const int st = blockIdx.x;   // 0..31 (64 seqs each)
  const int c = blockIdx.y;    // 0..31
  const int tid = threadIdx.x;
  const int sgl = st * 64;
  const int bi = sgl >> 9, d0 = sgl & 511;

  const float* W1Tg = wsr + OFF_W1T;
#pragma unroll
  for (int k = 0; k < 8; ++k) {
    const int e = tid + 256 * k;          // 2048 float4 over 128x64
    const int r = e >> 4, i4 = (e & 15) * 4;
    *(float4*)&W1s[r][i4] = *(const float4*)(W1Tg + (size_t)e * 4);
  }

  const float* ub = u + ((size_t)bi * L_SEQ + c * CH) * D_MODEL + d0;
  const int sy4 = (tid >> 4) * 4;   // s group (0..15)*4
  const int ix4 = (tid & 15) * 4;   // i group (0..15)*4

  float acc[4][4];
#pragma unroll
  for (int r = 0; r < 4; ++r)
#pragma unroll
    for (int cc = 0; cc < 4; ++cc) acc[r][cc] = 0.f;

  for (int h = 0; h < 2; ++h) {
    __syncthreads();
#pragma unroll
    for (int e4 = 0; e4 < 4; ++e4) {
      const int e = tid + 256 * e4;       // 1024 float4 over 64x64 u tile
      const int rr = e >> 4, s4 = (e & 15) * 4;
      *(float4*)&Us[rr][s4] =
          *(const float4*)(ub + (size_t)(h * 64 + rr) * D_MODEL + s4);
    }
    __syncthreads();
#pragma unroll 8
    for (int kk = 0; kk < 64; ++kk) {
      const float4 a = *(const float4*)&Us[kk][sy4];
      const float4 b = *(const float4*)&W1s[h * 64 + kk][ix4];
      const float av[4] = {a.x, a.y, a.z, a.w};
      const float bv[4] = {b.x, b.y, b.z, b.w};
#pragma unroll
      for (int ii = 0; ii < 4; ++ii)
#pragma unroll
        for (int jj = 0; jj < 4; ++jj) acc[ii][jj] += av[ii] * bv[jj];
    }
  }

  // write gx[c][s][i] (i contiguous)
  float* gb = gx + ((size_t)c * NSEQ + sgl) * 64;
#pragma unroll
  for (int j = 0; j < 4; ++j) {
    float4 v; v.x = acc[j][0]; v.y = acc[j][1]; v.z = acc[j][2]; v.w = acc[j][3];
    *(float4*)(gb + (size_t)(sy4 + j) * 64 + ix4) = v;
  }
}

// ===========================================================================
// k_scan: x_{c+1} = P x_c + g_c. One seq per wave, lane = state.
// 3-deep chunk prefetch pipeline. (unchanged)
// ===========================================================================
__global__ __launch_bounds__(256) void k_scan(
    const float* __restrict__ wsr, float* __restrict__ gx) {
  const int lane = threadIdx.x & 63, wv = threadIdx.x >> 6;
  const int s = blockIdx.x * 4 + wv;

  float p[64];
  {
    const float* pr = wsr + OFF_P + lane * 64;
#pragma unroll
    for (int j = 0; j < 64; j += 4) {
      const float4 v = *(const float4*)(pr + j);
      p[j] = v.x; p[j + 1] = v.y; p[j + 2] = v.z; p[j + 3] = v.w;
    }
  }

  const size_t CS = (size_t)NSEQ * 64;
  float* gs = gx + (size_t)s * 64 + lane;
  float x = 0.f;
  float g0 = gs[0];
  float g1 = gs[CS];
  float g2 = gs[2 * CS];
  for (int c = 0; c < NC; ++c) {
    const float gn = (c + 3 < NC) ? gs[(size_t)(c + 3) * CS] : 0.f;
    gs[(size_t)c * CS] = x;  // overwrite g[c] with pre-chunk state X_c
    float x0 = g0, x1 = 0.f;
#pragma unroll
    for (int j = 0; j < 64; j += 2) {
      x0 += p[j] * BC(x, j);
      x1 += p[j + 1] * BC(x, j + 1);
    }
    x = x0 + x1;
    g0 = g1; g1 = g2; g2 = gn;
  }
}

// ===========================================================================
// k_localout: y[c*128+r][s] = sum_{r'<=r} Kloc[r-r'] u[c*128+r'][s]
//                           + sum_i Wout[i][r] * X_c[i][s]
// 128r x 64s per block, 256 threads, 8x4 micro. LDS union 48KB:
//   phase A: Bs(u) 16K + KzS 4K  (Toeplitz a-side read from 4 shifted
//            kernel copies -> no 32KB As matrix)
//   phase B: Bs(X) 16K + As_W 32K (overwrites KzS after phase A)
// -> 3 blocks/CU (was 2), grid 1024 (was 512) -> 3 waves/SIMD.
// ===========================================================================
#define LO_BS(k, s)   LDSf[(k) * 64 + (s)]
#define LO_KZS        4096
#define LO_ASW(i, r)  LDSf[4096 + (i) * 128 + (r)]

__global__ __launch_bounds__(256) void k_localout(
    const float* __restrict__ u, const float* __restrict__ wsr,
    const float* __restrict__ gx, float* __restrict__ out) {
  __shared__ float LDSf[12288];   // 48KB

  const int sg = blockIdx.x;      // 0..31 (64 seqs each)
  const int c = blockIdx.y;       // 0..31 (chunk)
  const int sgl = sg * 64;
  const int bi = sgl >> 9, d0 = sgl & 511;

  const float* KzSg = wsr + OFF_KZS;
  const float* WoutG = wsr + OFF_WOUT;
  const float* ub = u + ((size_t)bi * L_SEQ + c * CH) * D_MODEL + d0;

  const int tid = threadIdx.x;
  const int ry8 = (tid >> 4) * 8;   // 8 rows (wave w owns rows w*32..w*32+31)
  const int sx4 = (tid & 15) * 4;   // 4 s-cols

  // stage KzS (1 float4/thread, 4KB)
  *(float4*)&LDSf[LO_KZS + tid * 4] = *(const float4*)(KzSg + tid * 4);

  float acc[8][4];
#pragma unroll
  for (int r = 0; r < 8; ++r)
#pragma unroll
    for (int cc = 0; cc < 4; ++cc) acc[r][cc] = 0.f;

  // phase A: within-chunk Toeplitz, K = 128 in two 64-k stages
  for (int kt = 0; kt < 2; ++kt) {
    const int k0 = kt * 64;
#pragma unroll
    for (int e4 = 0; e4 < 4; ++e4) {
      const int e = tid + 256 * e4;          // 1024 float4 over 64x64 u tile
      const int kk = e >> 4, s4 = (e & 15) * 4;
      *(float4*)&LO_BS(kk, s4) =
          *(const float4*)(ub + (size_t)(k0 + kk) * D_MODEL + s4);
    }
    __syncthreads();
    const int base = 128 - k0;
    // kt=1: rows <64 have zero contribution (guard zone); wave-uniform skip.
    if (kt == 0 || ry8 >= 64) {
#pragma unroll 8
      for (int kk = 0; kk < 64; ++kk) {
        const int p = kk & 3;
        const int idx = base + ry8 - kk + p;   // 16B-aligned by construction
        const float4 a0 = *(const float4*)&LDSf[LO_KZS + p * 256 + idx];
        const float4 a1 = *(const float4*)&LDSf[LO_KZS + p * 256 + idx + 4];
        const float4 b = *(const float4*)&LO_BS(kk, sx4);
        const float av[8] = {a0.x, a0.y, a0.z, a0.w, a1.x, a1.y, a1.z, a1.w};
        const float bv[4] = {b.x, b.y, b.z, b.w};
#pragma unroll
        for (int ii = 0; ii < 8; ++ii)
#pragma unroll
          for (int jj = 0; jj < 4; ++jj) acc[ii][jj] += av[ii] * bv[jj];
      }
    }
    __syncthreads();
  }

  // phase B: Wout * X_c
  {
    // As_W[i][r] = Wout (64x128, 32KB; overwrites KzS region)
#pragma unroll
    for (int e8 = 0; e8 < 8; ++e8) {
      const int e = tid + 256 * e8;          // 2048 float4
      const int i_ = e >> 5, r4 = (e & 31) * 4;
      *(float4*)&LO_ASW(i_, r4) = *(const float4*)(WoutG + i_ * 128 + r4);
    }
    // Bs = X_c[i][s] from gx[c][s][i]; sl-major mapping -> conflict-free
    // scalar writes (banks = sl%32, 2-way) and L1-served strided reads.
    const float* xc = gx + ((size_t)c * NSEQ + sgl) * 64;
#pragma unroll
    for (int e4 = 0; e4 < 4; ++e4) {
      const int e = tid + 256 * e4;          // 1024 float4 = 4096 elems
      const int sl = e & 63, i4 = ((e >> 6) & 15) * 4;
      const float4 v = *(const float4*)(xc + (size_t)sl * 64 + i4);
      LO_BS(i4 + 0, sl) = v.x;
      LO_BS(i4 + 1, sl) = v.y;
      LO_BS(i4 + 2, sl) = v.z;
      LO_BS(i4 + 3, sl) = v.w;
    }
    __syncthreads();
#pragma unroll 8
    for (int kk = 0; kk < 64; ++kk) {
      const float4 a0 = *(const float4*)&LO_ASW(kk, ry8);
      const float4 a1 = *(const float4*)&LO_ASW(kk, ry8 + 4);
      const float4 b = *(const float4*)&LO_BS(kk, sx4);
      const float av[8] = {a0.x, a0.y, a0.z, a0.w, a1.x, a1.y, a1.z, a1.w};
      const float bv[4] = {b.x, b.y, b.z, b.w};
#pragma unroll
      for (int ii = 0; ii < 8; ++ii)
#pragma unroll
        for (int jj = 0; jj < 4; ++jj) acc[ii][jj] += av[ii] * bv[jj];
    }
  }

  // epilogue: rows ry8..ry8+7, cols sx4..sx4+3
  float* ob = out + ((size_t)bi * L_SEQ + c * CH) * D_MODEL + d0;
#pragma unroll
  for (int r = 0; r < 8; ++r) {
    float4 v; v.x = acc[r][0]; v.y = acc[r][1]; v.z = acc[r][2]; v.w = acc[r][3];
    *(float4*)(ob + (size_t)(ry8 + r) * D_MODEL + sx4) = v;
  }
}

extern "C" void kernel_launch(void* const* d_in, const int* in_sizes, int n_in,
                              void* d_out, int out_size, void* d_ws,
                              size_t ws_size, hipStream_t stream) {
  const float* u = (const float*)d_in[0];   // (4, 4096, 512)
  const float* A = (const float*)d_in[1];   // (64, 64)
  const float* B = (const float*)d_in[2];   // (64, 1)
  const float* C = (const float*)d_in[3];   // (1, 64)
  float* out = (float*)d_out;
  float* ws = (float*)d_ws;                 // needs ~16.9 MB
  float* gx = ws + OFF_GX;

  k_prep<<<1, 256, 0, stream>>>(A, B, C, ws);
  k_proj<<<dim3(32, 32), 256, 0, stream>>>(u, ws, gx);
  k_scan<<<512, 256, 0, stream>>>(ws, gx);
  k_localout<<<dim3(32, 32), 256, 0, stream>>>(u, ws, gx, out);
}